// Round 13
// baseline (266.224 us; speedup 1.0000x reference)
//
#include <hip/hip_runtime.h>
#include <hip/hip_bf16.h>
#include <stdint.h>

typedef __attribute__((ext_vector_type(8))) __bf16 bf16x8;
typedef __attribute__((ext_vector_type(4))) float f32x4;
typedef __attribute__((ext_vector_type(16))) float f32x16;
typedef unsigned short u16;

#define MFMA16(a, b, c) __builtin_amdgcn_mfma_f32_16x16x32_bf16((a), (b), (c), 0, 0, 0)
#define MFMA32(a, b, c) __builtin_amdgcn_mfma_f32_32x32x16_bf16((a), (b), (c), 0, 0, 0)

__device__ __forceinline__ u16 f32_to_bf16_rne(float f) {
  union { float f; uint32_t u; } v; v.f = f;
  uint32_t u = v.u;
  u += 0x7fffu + ((u >> 16) & 1u);
  return (u16)(u >> 16);
}

__device__ __forceinline__ void gl_lds16(const void* g, void* l) {
  __builtin_amdgcn_global_load_lds(
      (const __attribute__((address_space(1))) void*)(uintptr_t)g,
      (__attribute__((address_space(3))) void*)(uintptr_t)l,
      16, 0, 0);
}

__device__ __forceinline__ float fast_exp2(float x) {
#if __has_builtin(__builtin_amdgcn_exp2f)
  return __builtin_amdgcn_exp2f(x);
#else
  return exp2f(x);
#endif
}

__device__ __forceinline__ uint32_t cvt_pk_bf16(float a, float b) {
  uint32_t r;
  asm("v_cvt_pk_bf16_f32 %0, %1, %2" : "=v"(r) : "v"(a), "v"(b));
  return r;
}

// ---------------------------------------------------------------- fused cast
__global__ void cast_all_kernel(const float* __restrict__ x, const float* __restrict__ Wk,
                                const float* __restrict__ Wq, const float* __restrict__ Wv,
                                const float* __restrict__ Wo, u16* __restrict__ xb,
                                u16* __restrict__ wqkv, u16* __restrict__ wob) {
  const int i = blockIdx.x * 256 + threadIdx.x;
  const float* src; u16* dst; int off;
  if (i < 2097152)      { src = x;  dst = xb;             off = i; }
  else if (i < 2359296) { src = Wk; dst = wqkv;           off = i - 2097152; }
  else if (i < 2621440) { src = Wq; dst = wqkv + 1048576; off = i - 2359296; }
  else if (i < 2883584) { src = Wv; dst = wqkv + 2097152; off = i - 2621440; }
  else                  { src = Wo; dst = wob;            off = i - 2883584; }
  float4 v = reinterpret_cast<const float4*>(src)[off];
  ushort4 o;
  o.x = f32_to_bf16_rne(v.x);
  o.y = f32_to_bf16_rne(v.y);
  o.z = f32_to_bf16_rne(v.z);
  o.w = f32_to_bf16_rne(v.w);
  reinterpret_cast<ushort4*>(dst)[off] = o;
}

// ---------------------------------------------------------------- GEMM (B^T)
// 128x128 tile m97-structure; used for the FINAL projection only.
template <int FINAL>
__global__ __launch_bounds__(256, 2) void gemm_bt_kernel(
    const u16* __restrict__ A, const u16* __restrict__ Bt,
    void* __restrict__ Cout, const float* __restrict__ bias, int M, int N, int K) {
  __shared__ __attribute__((aligned(16))) u16 As[128 * 32];
  __shared__ __attribute__((aligned(16))) u16 Bs[128 * 32];
  const int tid = threadIdx.x;
  const int lane = tid & 63;
  const int wid = tid >> 6;
  const int wr = wid >> 1, wc = wid & 1;
  const int m0 = blockIdx.y * 128, n0 = blockIdx.x * 128;

  f32x4 acc[4][4] = {};

  const int sr = lane >> 2;
  const int scc = lane & 3;
  const int sh = (sr ^ (sr >> 2)) & 3;
  const int sc = ((scc ^ sh) << 3);
  const int rl = lane & 15;
  const int rh = (rl ^ (rl >> 2)) & 3;
  const int cpr = (((lane >> 4) ^ rh) << 4);

  for (int k0 = 0; k0 < K; k0 += 32) {
    __syncthreads();
#pragma unroll
    for (int i = 0; i < 2; ++i) {
      const int c = wid * 2 + i;
      const int row = c * 16 + sr;
      gl_lds16(A + (size_t)(m0 + row) * K + k0 + sc, (char*)As + c * 1024);
      gl_lds16(Bt + (size_t)(n0 + row) * K + k0 + sc, (char*)Bs + c * 1024);
    }
    __syncthreads();

    bf16x8 af[4], bf[4];
#pragma unroll
    for (int mi = 0; mi < 4; ++mi)
      af[mi] = *(const bf16x8*)((const char*)As + (wr * 64 + mi * 16 + rl) * 64 + cpr);
#pragma unroll
    for (int ni = 0; ni < 4; ++ni)
      bf[ni] = *(const bf16x8*)((const char*)Bs + (wc * 64 + ni * 16 + rl) * 64 + cpr);
    __builtin_amdgcn_s_setprio(1);
#pragma unroll
    for (int mi = 0; mi < 4; ++mi)
#pragma unroll
      for (int ni = 0; ni < 4; ++ni)
        acc[mi][ni] = MFMA16(af[mi], bf[ni], acc[mi][ni]);
    __builtin_amdgcn_s_setprio(0);
  }

#pragma unroll
  for (int mi = 0; mi < 4; ++mi) {
#pragma unroll
    for (int ni = 0; ni < 4; ++ni) {
      const int row = m0 + wr * 64 + mi * 16 + ((lane >> 4) << 2);
      const int col = n0 + wc * 64 + ni * 16 + (lane & 15);
#pragma unroll
      for (int j = 0; j < 4; ++j) {
        if (FINAL) {
          reinterpret_cast<float*>(Cout)[(size_t)(row + j) * N + col] =
              acc[mi][ni][j] + bias[col];
        } else {
          reinterpret_cast<u16*>(Cout)[(size_t)(row + j) * N + col] =
              f32_to_bf16_rne(acc[mi][ni][j]);
        }
      }
    }
  }
}

// ---------------------------------------------------------------- GEMM 256^2 8-phase
// (validated r11; see header there for schedule + vmcnt audit.)
__device__ __forceinline__ void g256_stage(const u16* __restrict__ src, int b0,
                                           int half, int t, char* region, int K,
                                           int tid) {
  char* dst = region + half * 16384;
  const int w64 = tid & ~63;  // wave-uniform thread base
  const int lane = tid & 63;
#pragma unroll
  for (int j = 0; j < 2; ++j) {
    const int gbase = j * 512 + w64;  // wave-uniform granule base
    const int gI = gbase + lane;
    const int r = gI >> 3;
    const int c = ((gI & 7) ^ (r & 7)) * 8;
    gl_lds16(src + (size_t)(b0 + half * 128 + r) * K + t * 64 + c,
             dst + gbase * 16);
  }
}

template <int Q, bool LOADB, int VM>
__device__ __forceinline__ void g256_phase(
    char* lds, int slot, const u16* __restrict__ A, const u16* __restrict__ Bt,
    int m0, int n0, int K, int stT, int stHalf, bool stIsB, int stSlot,
    int wm, int wn, int l15, int l4, int tid,
    bf16x8 (&bf)[2][4], f32x4 (&acc)[8][4]) {
  const char* Ab = lds + slot * 65536 + wm * 16384;
  if (LOADB) {
    const char* Bb = lds + slot * 65536 + 32768 + (wn >> 1) * 16384;
#pragma unroll
    for (int kk = 0; kk < 2; ++kk)
#pragma unroll
      for (int ni = 0; ni < 4; ++ni) {
        const int lr = (wn & 1) * 64 + ni * 16 + l15;
        bf[kk][ni] = *(const bf16x8*)(Bb + lr * 128 + (((kk * 4 + l4) ^ (lr & 7)) << 4));
      }
  }
  bf16x8 af[2][2];
#pragma unroll
  for (int mi = 0; mi < 2; ++mi)
#pragma unroll
    for (int kk = 0; kk < 2; ++kk) {
      const int lr = (Q * 2 + mi) * 16 + l15;
      af[mi][kk] = *(const bf16x8*)(Ab + lr * 128 + (((kk * 4 + l4) ^ (lr & 7)) << 4));
    }
  {
    const u16* src = stIsB ? Bt : A;
    const int b0 = stIsB ? n0 : m0;
    char* region = lds + stSlot * 65536 + (stIsB ? 32768 : 0);
    g256_stage(src, b0, stHalf, stT, region, K, tid);
  }
  if (VM == 4) asm volatile("s_waitcnt vmcnt(4)" ::: "memory");
  __builtin_amdgcn_s_barrier();
  __builtin_amdgcn_s_setprio(1);
#pragma unroll
  for (int mi = 0; mi < 2; ++mi)
#pragma unroll
    for (int ni = 0; ni < 4; ++ni)
#pragma unroll
      for (int kk = 0; kk < 2; ++kk)
        acc[Q * 2 + mi][ni] = MFMA16(af[mi][kk], bf[kk][ni], acc[Q * 2 + mi][ni]);
  __builtin_amdgcn_s_setprio(0);
  __builtin_amdgcn_s_barrier();
}

__global__ __launch_bounds__(512) void gemm256_kernel(
    const u16* __restrict__ A, const u16* __restrict__ Bt, u16* __restrict__ C,
    int M, int N, int K) {
  __shared__ __attribute__((aligned(16))) char lds[131072];

  const int tid = threadIdx.x;
  const int lane = tid & 63;
  const int w = tid >> 6;
  const int wm = w >> 2, wn = w & 3;
  const int l15 = lane & 15, l4 = lane >> 4;

  const int bid = blockIdx.x;
  const int wg = (bid & 7) * (gridDim.x >> 3) + (bid >> 3);
  const int nbx = N >> 8;
  const int by = wg / nbx, bx = wg - by * nbx;
  const int m0 = by << 8, n0 = bx << 8;

  f32x4 acc[8][4] = {};
  bf16x8 bf[2][4];

  g256_stage(A, m0, 0, 0, lds, K, tid);
  g256_stage(A, m0, 1, 0, lds, K, tid);
  g256_stage(Bt, n0, 0, 0, lds + 32768, K, tid);
  g256_stage(Bt, n0, 1, 0, lds + 32768, K, tid);
  g256_stage(Bt, n0, 0, 1, lds + 65536 + 32768, K, tid);
  g256_stage(Bt, n0, 1, 1, lds + 65536 + 32768, K, tid);
  asm volatile("s_waitcnt vmcnt(4)" ::: "memory");
  __builtin_amdgcn_s_barrier();

  const int KT = K >> 6;
#pragma unroll 1
  for (int it = 0; it < (KT >> 1); ++it) {
    const int t1 = it * 2 + 1;
    int t2 = it * 2 + 2; if (t2 > KT - 1) t2 = KT - 1;
    int t3 = it * 2 + 3; if (t3 > KT - 1) t3 = KT - 1;
    g256_phase<0, true, -1>(lds, 0, A, Bt, m0, n0, K, t1, 0, false, 1, wm, wn, l15, l4, tid, bf, acc);
    g256_phase<1, false, -1>(lds, 0, A, Bt, m0, n0, K, t1, 1, false, 1, wm, wn, l15, l4, tid, bf, acc);
    g256_phase<2, false, -1>(lds, 0, A, Bt, m0, n0, K, t2, 0, true, 0, wm, wn, l15, l4, tid, bf, acc);
    g256_phase<3, false, 4>(lds, 0, A, Bt, m0, n0, K, t2, 1, true, 0, wm, wn, l15, l4, tid, bf, acc);
    g256_phase<0, true, -1>(lds, 1, A, Bt, m0, n0, K, t2, 0, false, 0, wm, wn, l15, l4, tid, bf, acc);
    g256_phase<1, false, -1>(lds, 1, A, Bt, m0, n0, K, t2, 1, false, 0, wm, wn, l15, l4, tid, bf, acc);
    g256_phase<2, false, -1>(lds, 1, A, Bt, m0, n0, K, t3, 0, true, 1, wm, wn, l15, l4, tid, bf, acc);
    g256_phase<3, false, 4>(lds, 1, A, Bt, m0, n0, K, t3, 1, true, 1, wm, wn, l15, l4, tid, bf, acc);
  }
  asm volatile("s_waitcnt vmcnt(0)" ::: "memory");

#pragma unroll
  for (int mi = 0; mi < 8; ++mi) {
#pragma unroll
    for (int ni = 0; ni < 4; ++ni) {
      const int row = m0 + wm * 128 + mi * 16 + l4 * 4;
      const int col = n0 + wn * 64 + ni * 16 + l15;
#pragma unroll
      for (int j = 0; j < 4; ++j)
        C[(size_t)(row + j) * N + col] = f32_to_bf16_rne(acc[mi][ni][j]);
    }
  }
}

// ---------------------------------------------------------------- attention
// r13: attn = r8/r11 kernel (validated 94.6us, 4-wave 128-row blocks, 32KB
// LDS, counted vmcnt) with a BALANCED block schedule: idx -> (q=idx>>8,
// bh=(idx>>2)&63, s=idx&3), ttile = {15-q, q, 11-q, 4+q}[s]. Any 4
// consecutive blocks share one bh (L2 locality) and have rank sum 30 ->
// every CU cohort totals 68 tile-iters (r11's order gave 56..80, makespan
// tracked 80). Pure permutation: bijective over (bh, ttile).
#define KQVS 3072
#define SCL 0.18033688011f /* 0.125 * log2(e) */
#define NEG (-1e30f)

__device__ __forceinline__ void v_load(uint4* vr, const u16* __restrict__ Vsrc,
                                       int s0, int tid) {
#pragma unroll
  for (int it = 0; it < 2; ++it) {
    const int idx = it * 256 + tid;
    const int g = idx & 7, srow = idx >> 3;
    vr[it] = *reinterpret_cast<const uint4*>(Vsrc + (size_t)(s0 + srow) * KQVS + g * 8);
  }
}

__device__ __forceinline__ void vt_write(u16* buf, const uint4* vr, int tid) {
#pragma unroll
  for (int it = 0; it < 2; ++it) {
    const int idx = it * 256 + tid;
    const int g = idx & 7, srow = idx >> 3;
    const u16* pv = reinterpret_cast<const u16*>(&vr[it]);
#pragma unroll
    for (int u = 0; u < 8; ++u) {
      const int ue = (u + g) & 7;
      const int d = g * 8 + ue;
      buf[((srow >> 3) * 64 + d) * 8 + (srow & 7)] = pv[ue];
    }
  }
}

__global__ __launch_bounds__(256, 3) void attn_kernel(
    const u16* __restrict__ KQV, u16* __restrict__ Ob) {
  __shared__ __attribute__((aligned(16))) char smem[32768];

  const int tid = threadIdx.x;
  const int lane = tid & 63;
  const int wv = tid >> 6;
  const int l31 = lane & 31;
  const int hh = lane >> 5;
  const bool lolane = (hh == 0);

  // balanced cohort schedule (see header)
  const int idx = blockIdx.x;
  const int q = idx >> 8;
  const int bh = (idx >> 2) & 63;
  const int s4 = idx & 3;
  int ttile;
  switch (s4) {
    case 0:  ttile = 15 - q; break;
    case 1:  ttile = q;      break;
    case 2:  ttile = 11 - q; break;
    default: ttile = 4 + q;  break;
  }
  const int b = bh >> 4, head = bh & 15;

  const size_t rbase = (size_t)b * 2048;
  const u16* Kh = KQV + rbase * KQVS + head * 64;
  const u16* Qh = Kh + 1024;
  const u16* Vh = Kh + 2048;
  u16* Oh = Ob + rbase * 1024 + head * 64;

  const int t0 = ttile * 128;
  const int nst = 2 * ttile + 2;
  const int t0w = t0 + wv * 32;
  const int tl = t0w + l31;
  const int rb4 = 4 * hh;

#pragma unroll
  for (int i = 0; i < 4; ++i) {
    const int ch = wv * 4 + i;
    const int cc = ch >> 1;
    const int trow = (ch & 1) * 64 + lane;
    gl_lds16(Kh + (size_t)(t0 + trow) * KQVS + cc * 8, smem + 16384 + ch * 1024);
  }
#pragma unroll
  for (int i = 0; i < 2; ++i) {
    const int ch = wv * 2 + i;
    gl_lds16(Qh + (size_t)lane * KQVS + ch * 8, smem + ch * 1024);
  }
  {
    uint4 vr0[2];
    v_load(vr0, Vh, 0, tid);
    vt_write((u16*)(smem + 8192), vr0, tid);
  }
  __syncthreads();

  bf16x8 kf[4];
  {
    const u16* Ksp = (const u16*)(smem + 16384);
#pragma unroll
    for (int kk = 0; kk < 4; ++kk)
      kf[kk] = *(const bf16x8*)(Ksp + ((kk * 2 + hh) * 128 + wv * 32 + l31) * 8);
  }
  __syncthreads();

  f32x16 oa0 = {}, oa1 = {};
  float l_run = 0.f;

#pragma unroll 1
  for (int st = 0; st < nst; ++st) {
    const int cur = st & 1;
    const int s0 = st * 64;
    const bool pref = (st + 1 < nst);
    uint4 vr[2];
    if (pref) {
      v_load(vr, Vh, s0 + 64, tid);
#pragma unroll
      for (int i = 0; i < 2; ++i) {
        const int ch = wv * 2 + i;
        gl_lds16(Qh + (size_t)(s0 + 64 + lane) * KQVS + ch * 8,
                 smem + (cur ^ 1) * 16384 + ch * 1024);
      }
    }

    const bool active = (s0 <= t0w + 31);
    f32x16 sa0 = {}, sa1 = {};
    if (active) {
      if (pref) {
        asm volatile("s_waitcnt vmcnt(4)" ::: "memory");
      } else {
        asm volatile("s_waitcnt vmcnt(0)" ::: "memory");
      }
      __builtin_amdgcn_sched_barrier(0);

      const u16* qb = (const u16*)(smem + cur * 16384);
      __builtin_amdgcn_s_setprio(1);
#pragma unroll
      for (int kk = 0; kk < 4; ++kk) {
        bf16x8 a0 = *(const bf16x8*)(qb + ((kk * 2 + hh) * 64 + l31) * 8);
        bf16x8 a1 = *(const bf16x8*)(qb + ((kk * 2 + hh) * 64 + 32 + l31) * 8);
        sa0 = MFMA32(a0, kf[kk], sa0);
        sa1 = MFMA32(a1, kf[kk], sa1);
      }
      __builtin_amdgcn_s_setprio(0);

      if (s0 + 63 > t0w) {
#pragma unroll
        for (int r = 0; r < 16; ++r) {
          const int rowloc = (r & 3) + 8 * (r >> 2) + rb4;
          if (s0 + rowloc > tl) sa0[r] = NEG;
          if (s0 + 32 + rowloc > tl) sa1[r] = NEG;
        }
      }

#pragma unroll
      for (int r = 0; r < 16; ++r) {
        sa0[r] = fast_exp2(sa0[r] * SCL);
        sa1[r] = fast_exp2(sa1[r] * SCL);
      }
      float rsA = ((sa0[0] + sa0[1]) + (sa0[2] + sa0[3])) +
                  ((sa0[4] + sa0[5]) + (sa0[6] + sa0[7]));
      float rsB = ((sa0[8] + sa0[9]) + (sa0[10] + sa0[11])) +
                  ((sa0[12] + sa0[13]) + (sa0[14] + sa0[15]));
      float rsC = ((sa1[0] + sa1[1]) + (sa1[2] + sa1[3])) +
                  ((sa1[4] + sa1[5]) + (sa1[6] + sa1[7]));
      float rsD = ((sa1[8] + sa1[9]) + (sa1[10] + sa1[11])) +
                  ((sa1[12] + sa1[13]) + (sa1[14] + sa1[15]));
      float rs = (rsA + rsB) + (rsC + rsD);
      rs += __shfl_xor(rs, 32);
      l_run += rs;
    }

    if (pref) vt_write((u16*)(smem + (cur ^ 1) * 16384 + 8192), vr, tid);

    if (active) {
      const u16* vb = (const u16*)(smem + cur * 16384 + 8192);
      __builtin_amdgcn_s_setprio(1);
#define PV_WINDOW(P, r0, w)                                                   \
  {                                                                           \
    uint32_t dA = cvt_pk_bf16(P[r0 + 0], P[r0 + 1]);                          \
    uint32_t dB = cvt_pk_bf16(P[r0 + 2], P[r0 + 3]);                          \
    uint32_t dC = cvt_pk_bf16(P[r0 + 4], P[r0 + 5]);                          \
    uint32_t dD = cvt_pk_bf16(P[r0 + 6], P[r0 + 7]);                          \
    uint32_t sdA = (uint32_t)__shfl_xor((int)dA, 32);                         \
    uint32_t sdB = (uint32_t)__shfl_xor((int)dB, 32);                         \
    uint32_t sdC = (uint32_t)__shfl_xor((int)dC, 32);                         \
    uint32_t sdD = (uint32_t)__shfl_xor((int)dD, 32);                         \
    union { uint32_t u[4]; bf16x8 v; } af;                                    \
    af.u[0] = lolane ? dA : sdC;                                              \
    af.u[1] = lolane ? dB : sdD;                                              \
    af.u[2] = lolane ? sdA : dC;                                              \
    af.u[3] = lolane ? sdB : dD;                                              \
    bf16x8 bv0 = *(const bf16x8*)(vb + ((2 * (w) + hh) * 64 + l31) * 8);      \
    bf16x8 bv1 = *(const bf16x8*)(vb + ((2 * (w) + hh) * 64 + 32 + l31) * 8); \
    oa0 = MFMA32(af.v, bv0, oa0);                                             \
    oa1 = MFMA32(af.v, bv1, oa1);                                             \
  }
      PV_WINDOW(sa0, 0, 0)
      PV_WINDOW(sa0, 8, 1)
      PV_WINDOW(sa1, 0, 2)
      PV_WINDOW(sa1, 8, 3)
#undef PV_WINDOW
      __builtin_amdgcn_s_setprio(0);
    }

    asm volatile("s_waitcnt lgkmcnt(0)" ::: "memory");
    __builtin_amdgcn_s_barrier();
  }

  {
    const float inv = 1.0f / l_run;
#pragma unroll
    for (int r = 0; r < 16; ++r) {
      const int rowloc = (r & 3) + 8 * (r >> 2) + rb4;
      const float ir = __shfl(inv, rowloc);
      const int trow = t0w + rowloc;
      Oh[(size_t)trow * 1024 + l31] = f32_to_bf16_rne(oa0[r] * ir);
      Oh[(size_t)trow * 1024 + 32 + l31] = f32_to_bf16_rne(oa1[r] * ir);
    }
  }
}

// ---------------------------------------------------------------- launch
extern "C" void kernel_launch(void* const* d_in, const int* in_sizes, int n_in,
                              void* d_out, int out_size, void* d_ws, size_t ws_size,
                              hipStream_t stream) {
  (void)in_sizes; (void)n_in; (void)out_size; (void)ws_size;
  const float* x  = (const float*)d_in[0];
  const float* Wk = (const float*)d_in[1];
  const float* Wq = (const float*)d_in[2];
  const float* Wv = (const float*)d_in[3];
  const float* Wo = (const float*)d_in[4];
  const float* bo = (const float*)d_in[5];
  float* out = (float*)d_out;

  char* ws = (char*)d_ws;
  u16* xb   = (u16*)(ws);                       // 16MB (x cast, later attn-out)
  u16* kqv  = (u16*)(ws + ((size_t)16 << 20));  // 48MB [8192 x 3072] K|Q|V
  u16* wqkv = (u16*)(ws + ((size_t)64 << 20));  // 6MB  [3072 x 1024]
  u16* wob  = (u16*)(ws + ((size_t)70 << 20));  // 2MB -> 72MB total

  cast_all_kernel<<<dim3(12288), 256, 0, stream>>>(x, Wk, Wq, Wv, Wo, xb, wqkv, wob);

  // fused K/Q/V projection: [8192,3072] = [8192,1024] x [3072,1024]^T
  gemm256_kernel<<<dim3(384), 512, 0, stream>>>(xb, wqkv, kqv, 8192, 3072, 1024);

  // attention (writes into xb)
  attn_kernel<<<dim3(1024), 256, 0, stream>>>(kqv, xb);

  // final projection + bias, f32 out
  gemm_bt_kernel<1><<<dim3(8, 64), 256, 0, stream>>>(xb, wob, out, bo, 8192, 1024, 1024);
}

// Round 14
// 186.138 us; speedup vs baseline: 1.4303x; 1.4303x over previous
//
#include <hip/hip_runtime.h>
#include <hip/hip_bf16.h>
#include <stdint.h>

typedef __attribute__((ext_vector_type(8))) __bf16 bf16x8;
typedef __attribute__((ext_vector_type(4))) float f32x4;
typedef __attribute__((ext_vector_type(16))) float f32x16;
typedef unsigned short u16;

#define MFMA16(a, b, c) __builtin_amdgcn_mfma_f32_16x16x32_bf16((a), (b), (c), 0, 0, 0)
#define MFMA32(a, b, c) __builtin_amdgcn_mfma_f32_32x32x16_bf16((a), (b), (c), 0, 0, 0)

__device__ __forceinline__ u16 f32_to_bf16_rne(float f) {
  union { float f; uint32_t u; } v; v.f = f;
  uint32_t u = v.u;
  u += 0x7fffu + ((u >> 16) & 1u);
  return (u16)(u >> 16);
}

__device__ __forceinline__ void gl_lds16(const void* g, void* l) {
  __builtin_amdgcn_global_load_lds(
      (const __attribute__((address_space(1))) void*)(uintptr_t)g,
      (__attribute__((address_space(3))) void*)(uintptr_t)l,
      16, 0, 0);
}

__device__ __forceinline__ float fast_exp2(float x) {
#if __has_builtin(__builtin_amdgcn_exp2f)
  return __builtin_amdgcn_exp2f(x);
#else
  return exp2f(x);
#endif
}

__device__ __forceinline__ uint32_t cvt_pk_bf16(float a, float b) {
  uint32_t r;
  asm("v_cvt_pk_bf16_f32 %0, %1, %2" : "=v"(r) : "v"(a), "v"(b));
  return r;
}

// ---------------------------------------------------------------- fused cast
__global__ void cast_all_kernel(const float* __restrict__ x, const float* __restrict__ Wk,
                                const float* __restrict__ Wq, const float* __restrict__ Wv,
                                const float* __restrict__ Wo, u16* __restrict__ xb,
                                u16* __restrict__ wqkv, u16* __restrict__ wob) {
  const int i = blockIdx.x * 256 + threadIdx.x;
  const float* src; u16* dst; int off;
  if (i < 2097152)      { src = x;  dst = xb;             off = i; }
  else if (i < 2359296) { src = Wk; dst = wqkv;           off = i - 2097152; }
  else if (i < 2621440) { src = Wq; dst = wqkv + 1048576; off = i - 2359296; }
  else if (i < 2883584) { src = Wv; dst = wqkv + 2097152; off = i - 2621440; }
  else                  { src = Wo; dst = wob;            off = i - 2883584; }
  float4 v = reinterpret_cast<const float4*>(src)[off];
  ushort4 o;
  o.x = f32_to_bf16_rne(v.x);
  o.y = f32_to_bf16_rne(v.y);
  o.z = f32_to_bf16_rne(v.z);
  o.w = f32_to_bf16_rne(v.w);
  reinterpret_cast<ushort4*>(dst)[off] = o;
}

// ---------------------------------------------------------------- GEMM (B^T)
// 128x128 tile m97-structure; used for the FINAL projection only.
template <int FINAL>
__global__ __launch_bounds__(256, 2) void gemm_bt_kernel(
    const u16* __restrict__ A, const u16* __restrict__ Bt,
    void* __restrict__ Cout, const float* __restrict__ bias, int M, int N, int K) {
  __shared__ __attribute__((aligned(16))) u16 As[128 * 32];
  __shared__ __attribute__((aligned(16))) u16 Bs[128 * 32];
  const int tid = threadIdx.x;
  const int lane = tid & 63;
  const int wid = tid >> 6;
  const int wr = wid >> 1, wc = wid & 1;
  const int m0 = blockIdx.y * 128, n0 = blockIdx.x * 128;

  f32x4 acc[4][4] = {};

  const int sr = lane >> 2;
  const int scc = lane & 3;
  const int sh = (sr ^ (sr >> 2)) & 3;
  const int sc = ((scc ^ sh) << 3);
  const int rl = lane & 15;
  const int rh = (rl ^ (rl >> 2)) & 3;
  const int cpr = (((lane >> 4) ^ rh) << 4);

  for (int k0 = 0; k0 < K; k0 += 32) {
    __syncthreads();
#pragma unroll
    for (int i = 0; i < 2; ++i) {
      const int c = wid * 2 + i;
      const int row = c * 16 + sr;
      gl_lds16(A + (size_t)(m0 + row) * K + k0 + sc, (char*)As + c * 1024);
      gl_lds16(Bt + (size_t)(n0 + row) * K + k0 + sc, (char*)Bs + c * 1024);
    }
    __syncthreads();

    bf16x8 af[4], bf[4];
#pragma unroll
    for (int mi = 0; mi < 4; ++mi)
      af[mi] = *(const bf16x8*)((const char*)As + (wr * 64 + mi * 16 + rl) * 64 + cpr);
#pragma unroll
    for (int ni = 0; ni < 4; ++ni)
      bf[ni] = *(const bf16x8*)((const char*)Bs + (wc * 64 + ni * 16 + rl) * 64 + cpr);
    __builtin_amdgcn_s_setprio(1);
#pragma unroll
    for (int mi = 0; mi < 4; ++mi)
#pragma unroll
      for (int ni = 0; ni < 4; ++ni)
        acc[mi][ni] = MFMA16(af[mi], bf[ni], acc[mi][ni]);
    __builtin_amdgcn_s_setprio(0);
  }

#pragma unroll
  for (int mi = 0; mi < 4; ++mi) {
#pragma unroll
    for (int ni = 0; ni < 4; ++ni) {
      const int row = m0 + wr * 64 + mi * 16 + ((lane >> 4) << 2);
      const int col = n0 + wc * 64 + ni * 16 + (lane & 15);
#pragma unroll
      for (int j = 0; j < 4; ++j) {
        if (FINAL) {
          reinterpret_cast<float*>(Cout)[(size_t)(row + j) * N + col] =
              acc[mi][ni][j] + bias[col];
        } else {
          reinterpret_cast<u16*>(Cout)[(size_t)(row + j) * N + col] =
              f32_to_bf16_rne(acc[mi][ni][j]);
        }
      }
    }
  }
}

// ---------------------------------------------------------------- GEMM 256^2 8-phase
// (validated r11; schedule: iter computes kt=2i in slot0 [ph1-4], kt+1 in
// slot1 [ph5-8]; stages ph1:A0(kt+1)->s1 ph2:A1->s1 ph3:B0(kt+2)->s0
// ph4:B1->s0 ph5:A0(kt+2)->s0 ph6:A1->s0 ph7:B0(kt+3)->s1 ph8:B1->s1.
// vmcnt(4)@ph4 retires slot1 B+A; vmcnt(4)@ph8 retires slot0 B+A.)
__device__ __forceinline__ void g256_stage(const u16* __restrict__ src, int b0,
                                           int half, int t, char* region, int K,
                                           int tid) {
  char* dst = region + half * 16384;
  const int w64 = tid & ~63;  // wave-uniform thread base
  const int lane = tid & 63;
#pragma unroll
  for (int j = 0; j < 2; ++j) {
    const int gbase = j * 512 + w64;  // wave-uniform granule base
    const int gI = gbase + lane;
    const int r = gI >> 3;
    const int c = ((gI & 7) ^ (r & 7)) * 8;
    gl_lds16(src + (size_t)(b0 + half * 128 + r) * K + t * 64 + c,
             dst + gbase * 16);
  }
}

template <int Q, bool LOADB, int VM>
__device__ __forceinline__ void g256_phase(
    char* lds, int slot, const u16* __restrict__ A, const u16* __restrict__ Bt,
    int m0, int n0, int K, int stT, int stHalf, bool stIsB, int stSlot,
    int wm, int wn, int l15, int l4, int tid,
    bf16x8 (&bf)[2][4], f32x4 (&acc)[8][4]) {
  const char* Ab = lds + slot * 65536 + wm * 16384;
  if (LOADB) {
    const char* Bb = lds + slot * 65536 + 32768 + (wn >> 1) * 16384;
#pragma unroll
    for (int kk = 0; kk < 2; ++kk)
#pragma unroll
      for (int ni = 0; ni < 4; ++ni) {
        const int lr = (wn & 1) * 64 + ni * 16 + l15;
        bf[kk][ni] = *(const bf16x8*)(Bb + lr * 128 + (((kk * 4 + l4) ^ (lr & 7)) << 4));
      }
  }
  bf16x8 af[2][2];
#pragma unroll
  for (int mi = 0; mi < 2; ++mi)
#pragma unroll
    for (int kk = 0; kk < 2; ++kk) {
      const int lr = (Q * 2 + mi) * 16 + l15;
      af[mi][kk] = *(const bf16x8*)(Ab + lr * 128 + (((kk * 4 + l4) ^ (lr & 7)) << 4));
    }
  {
    const u16* src = stIsB ? Bt : A;
    const int b0 = stIsB ? n0 : m0;
    char* region = lds + stSlot * 65536 + (stIsB ? 32768 : 0);
    g256_stage(src, b0, stHalf, stT, region, K, tid);
  }
  if (VM == 4) asm volatile("s_waitcnt vmcnt(4)" ::: "memory");
  __builtin_amdgcn_s_barrier();
  __builtin_amdgcn_s_setprio(1);
#pragma unroll
  for (int mi = 0; mi < 2; ++mi)
#pragma unroll
    for (int ni = 0; ni < 4; ++ni)
#pragma unroll
      for (int kk = 0; kk < 2; ++kk)
        acc[Q * 2 + mi][ni] = MFMA16(af[mi][kk], bf[kk][ni], acc[Q * 2 + mi][ni]);
  __builtin_amdgcn_s_setprio(0);
  __builtin_amdgcn_s_barrier();
}

__global__ __launch_bounds__(512) void gemm256_kernel(
    const u16* __restrict__ A, const u16* __restrict__ Bt, u16* __restrict__ C,
    int M, int N, int K) {
  __shared__ __attribute__((aligned(16))) char lds[131072];

  const int tid = threadIdx.x;
  const int lane = tid & 63;
  const int w = tid >> 6;
  const int wm = w >> 2, wn = w & 3;
  const int l15 = lane & 15, l4 = lane >> 4;

  const int bid = blockIdx.x;
  const int wg = (bid & 7) * (gridDim.x >> 3) + (bid >> 3);
  const int nbx = N >> 8;
  const int by = wg / nbx, bx = wg - by * nbx;
  const int m0 = by << 8, n0 = bx << 8;

  f32x4 acc[8][4] = {};
  bf16x8 bf[2][4];

  g256_stage(A, m0, 0, 0, lds, K, tid);
  g256_stage(A, m0, 1, 0, lds, K, tid);
  g256_stage(Bt, n0, 0, 0, lds + 32768, K, tid);
  g256_stage(Bt, n0, 1, 0, lds + 32768, K, tid);
  g256_stage(Bt, n0, 0, 1, lds + 65536 + 32768, K, tid);
  g256_stage(Bt, n0, 1, 1, lds + 65536 + 32768, K, tid);
  asm volatile("s_waitcnt vmcnt(4)" ::: "memory");
  __builtin_amdgcn_s_barrier();

  const int KT = K >> 6;
#pragma unroll 1
  for (int it = 0; it < (KT >> 1); ++it) {
    const int t1 = it * 2 + 1;
    int t2 = it * 2 + 2; if (t2 > KT - 1) t2 = KT - 1;
    int t3 = it * 2 + 3; if (t3 > KT - 1) t3 = KT - 1;
    g256_phase<0, true, -1>(lds, 0, A, Bt, m0, n0, K, t1, 0, false, 1, wm, wn, l15, l4, tid, bf, acc);
    g256_phase<1, false, -1>(lds, 0, A, Bt, m0, n0, K, t1, 1, false, 1, wm, wn, l15, l4, tid, bf, acc);
    g256_phase<2, false, -1>(lds, 0, A, Bt, m0, n0, K, t2, 0, true, 0, wm, wn, l15, l4, tid, bf, acc);
    g256_phase<3, false, 4>(lds, 0, A, Bt, m0, n0, K, t2, 1, true, 0, wm, wn, l15, l4, tid, bf, acc);
    g256_phase<0, true, -1>(lds, 1, A, Bt, m0, n0, K, t2, 0, false, 0, wm, wn, l15, l4, tid, bf, acc);
    g256_phase<1, false, -1>(lds, 1, A, Bt, m0, n0, K, t2, 1, false, 0, wm, wn, l15, l4, tid, bf, acc);
    g256_phase<2, false, -1>(lds, 1, A, Bt, m0, n0, K, t3, 0, true, 1, wm, wn, l15, l4, tid, bf, acc);
    g256_phase<3, false, 4>(lds, 1, A, Bt, m0, n0, K, t3, 1, true, 1, wm, wn, l15, l4, tid, bf, acc);
  }
  asm volatile("s_waitcnt vmcnt(0)" ::: "memory");

#pragma unroll
  for (int mi = 0; mi < 8; ++mi) {
#pragma unroll
    for (int ni = 0; ni < 4; ++ni) {
      const int row = m0 + wm * 128 + mi * 16 + l4 * 4;
      const int col = n0 + wn * 64 + ni * 16 + l15;
#pragma unroll
      for (int j = 0; j < 4; ++j)
        C[(size_t)(row + j) * N + col] = f32_to_bf16_rne(acc[mi][ni][j]);
    }
  }
}

// ---------------------------------------------------------------- attention
// r11 kernel restored byte-for-byte (validated 94.6us x4): 4-wave 128-row
// blocks, QK transposed 32x32x16, lane-local no-max softmax, reg-resident P,
// Ks-alias 32KB LDS, counted vmcnt + raw barrier, LPT + XCD-grouped (b,h)
// mapping (bh = (idx%8)*8 + ... keeps each XCD on 8 heads -> L2-resident
// K/Q/V; r13's "balanced" remap broke this and tripled HBM fetch).
#define KQVS 3072
#define SCL 0.18033688011f /* 0.125 * log2(e) */
#define NEG (-1e30f)

__device__ __forceinline__ void v_load(uint4* vr, const u16* __restrict__ Vsrc,
                                       int s0, int tid) {
#pragma unroll
  for (int it = 0; it < 2; ++it) {
    const int idx = it * 256 + tid;
    const int g = idx & 7, srow = idx >> 3;
    vr[it] = *reinterpret_cast<const uint4*>(Vsrc + (size_t)(s0 + srow) * KQVS + g * 8);
  }
}

__device__ __forceinline__ void vt_write(u16* buf, const uint4* vr, int tid) {
#pragma unroll
  for (int it = 0; it < 2; ++it) {
    const int idx = it * 256 + tid;
    const int g = idx & 7, srow = idx >> 3;
    const u16* pv = reinterpret_cast<const u16*>(&vr[it]);
#pragma unroll
    for (int u = 0; u < 8; ++u) {
      const int ue = (u + g) & 7;
      const int d = g * 8 + ue;
      buf[((srow >> 3) * 64 + d) * 8 + (srow & 7)] = pv[ue];
    }
  }
}

__global__ __launch_bounds__(256, 3) void attn_kernel(
    const u16* __restrict__ KQV, u16* __restrict__ Ob) {
  __shared__ __attribute__((aligned(16))) char smem[32768];

  const int tid = threadIdx.x;
  const int lane = tid & 63;
  const int wv = tid >> 6;
  const int l31 = lane & 31;
  const int hh = lane >> 5;
  const bool lolane = (hh == 0);

  const int idx = blockIdx.x;
  const int ttile = 15 - (idx >> 6);
  const int bhpos = idx & 63;
  const int bh = (bhpos & 7) * 8 + (bhpos >> 3);
  const int b = bh >> 4, head = bh & 15;

  const size_t rbase = (size_t)b * 2048;
  const u16* Kh = KQV + rbase * KQVS + head * 64;
  const u16* Qh = Kh + 1024;
  const u16* Vh = Kh + 2048;
  u16* Oh = Ob + rbase * 1024 + head * 64;

  const int t0 = ttile * 128;
  const int nst = 2 * ttile + 2;
  const int t0w = t0 + wv * 32;
  const int tl = t0w + l31;
  const int rb4 = 4 * hh;

#pragma unroll
  for (int i = 0; i < 4; ++i) {
    const int ch = wv * 4 + i;
    const int cc = ch >> 1;
    const int trow = (ch & 1) * 64 + lane;
    gl_lds16(Kh + (size_t)(t0 + trow) * KQVS + cc * 8, smem + 16384 + ch * 1024);
  }
#pragma unroll
  for (int i = 0; i < 2; ++i) {
    const int ch = wv * 2 + i;
    gl_lds16(Qh + (size_t)lane * KQVS + ch * 8, smem + ch * 1024);
  }
  {
    uint4 vr0[2];
    v_load(vr0, Vh, 0, tid);
    vt_write((u16*)(smem + 8192), vr0, tid);
  }
  __syncthreads();

  bf16x8 kf[4];
  {
    const u16* Ksp = (const u16*)(smem + 16384);
#pragma unroll
    for (int kk = 0; kk < 4; ++kk)
      kf[kk] = *(const bf16x8*)(Ksp + ((kk * 2 + hh) * 128 + wv * 32 + l31) * 8);
  }
  __syncthreads();

  f32x16 oa0 = {}, oa1 = {};
  float l_run = 0.f;

#pragma unroll 1
  for (int st = 0; st < nst; ++st) {
    const int cur = st & 1;
    const int s0 = st * 64;
    const bool pref = (st + 1 < nst);
    uint4 vr[2];
    if (pref) {
      v_load(vr, Vh, s0 + 64, tid);
#pragma unroll
      for (int i = 0; i < 2; ++i) {
        const int ch = wv * 2 + i;
        gl_lds16(Qh + (size_t)(s0 + 64 + lane) * KQVS + ch * 8,
                 smem + (cur ^ 1) * 16384 + ch * 1024);
      }
    }

    const bool active = (s0 <= t0w + 31);
    f32x16 sa0 = {}, sa1 = {};
    if (active) {
      if (pref) {
        asm volatile("s_waitcnt vmcnt(4)" ::: "memory");
      } else {
        asm volatile("s_waitcnt vmcnt(0)" ::: "memory");
      }
      __builtin_amdgcn_sched_barrier(0);

      const u16* qb = (const u16*)(smem + cur * 16384);
      __builtin_amdgcn_s_setprio(1);
#pragma unroll
      for (int kk = 0; kk < 4; ++kk) {
        bf16x8 a0 = *(const bf16x8*)(qb + ((kk * 2 + hh) * 64 + l31) * 8);
        bf16x8 a1 = *(const bf16x8*)(qb + ((kk * 2 + hh) * 64 + 32 + l31) * 8);
        sa0 = MFMA32(a0, kf[kk], sa0);
        sa1 = MFMA32(a1, kf[kk], sa1);
      }
      __builtin_amdgcn_s_setprio(0);

      if (s0 + 63 > t0w) {
#pragma unroll
        for (int r = 0; r < 16; ++r) {
          const int rowloc = (r & 3) + 8 * (r >> 2) + rb4;
          if (s0 + rowloc > tl) sa0[r] = NEG;
          if (s0 + 32 + rowloc > tl) sa1[r] = NEG;
        }
      }

#pragma unroll
      for (int r = 0; r < 16; ++r) {
        sa0[r] = fast_exp2(sa0[r] * SCL);
        sa1[r] = fast_exp2(sa1[r] * SCL);
      }
      float rsA = ((sa0[0] + sa0[1]) + (sa0[2] + sa0[3])) +
                  ((sa0[4] + sa0[5]) + (sa0[6] + sa0[7]));
      float rsB = ((sa0[8] + sa0[9]) + (sa0[10] + sa0[11])) +
                  ((sa0[12] + sa0[13]) + (sa0[14] + sa0[15]));
      float rsC = ((sa1[0] + sa1[1]) + (sa1[2] + sa1[3])) +
                  ((sa1[4] + sa1[5]) + (sa1[6] + sa1[7]));
      float rsD = ((sa1[8] + sa1[9]) + (sa1[10] + sa1[11])) +
                  ((sa1[12] + sa1[13]) + (sa1[14] + sa1[15]));
      float rs = (rsA + rsB) + (rsC + rsD);
      rs += __shfl_xor(rs, 32);
      l_run += rs;
    }

    if (pref) vt_write((u16*)(smem + (cur ^ 1) * 16384 + 8192), vr, tid);

    if (active) {
      const u16* vb = (const u16*)(smem + cur * 16384 + 8192);
      __builtin_amdgcn_s_setprio(1);
#define PV_WINDOW(P, r0, w)                                                   \
  {                                                                           \
    uint32_t dA = cvt_pk_bf16(P[r0 + 0], P[r0 + 1]);                          \
    uint32_t dB = cvt_pk_bf16(P[r0 + 2], P[r0 + 3]);                          \
    uint32_t dC = cvt_pk_bf16(P[r0 + 4], P[r0 + 5]);                          \
    uint32_t dD = cvt_pk_bf16(P[r0 + 6], P[r0 + 7]);                          \
    uint32_t sdA = (uint32_t)__shfl_xor((int)dA, 32);                         \
    uint32_t sdB = (uint32_t)__shfl_xor((int)dB, 32);                         \
    uint32_t sdC = (uint32_t)__shfl_xor((int)dC, 32);                         \
    uint32_t sdD = (uint32_t)__shfl_xor((int)dD, 32);                         \
    union { uint32_t u[4]; bf16x8 v; } af;                                    \
    af.u[0] = lolane ? dA : sdC;                                              \
    af.u[1] = lolane ? dB : sdD;                                              \
    af.u[2] = lolane ? sdA : dC;                                              \
    af.u[3] = lolane ? sdB : dD;                                              \
    bf16x8 bv0 = *(const bf16x8*)(vb + ((2 * (w) + hh) * 64 + l31) * 8);      \
    bf16x8 bv1 = *(const bf16x8*)(vb + ((2 * (w) + hh) * 64 + 32 + l31) * 8); \
    oa0 = MFMA32(af.v, bv0, oa0);                                             \
    oa1 = MFMA32(af.v, bv1, oa1);                                             \
  }
      PV_WINDOW(sa0, 0, 0)
      PV_WINDOW(sa0, 8, 1)
      PV_WINDOW(sa1, 0, 2)
      PV_WINDOW(sa1, 8, 3)
#undef PV_WINDOW
      __builtin_amdgcn_s_setprio(0);
    }

    asm volatile("s_waitcnt lgkmcnt(0)" ::: "memory");
    __builtin_amdgcn_s_barrier();
  }

  {
    const float inv = 1.0f / l_run;
#pragma unroll
    for (int r = 0; r < 16; ++r) {
      const int rowloc = (r & 3) + 8 * (r >> 2) + rb4;
      const float ir = __shfl(inv, rowloc);
      const int trow = t0w + rowloc;
      Oh[(size_t)trow * 1024 + l31] = f32_to_bf16_rne(oa0[r] * ir);
      Oh[(size_t)trow * 1024 + 32 + l31] = f32_to_bf16_rne(oa1[r] * ir);
    }
  }
}

// ---------------------------------------------------------------- launch
extern "C" void kernel_launch(void* const* d_in, const int* in_sizes, int n_in,
                              void* d_out, int out_size, void* d_ws, size_t ws_size,
                              hipStream_t stream) {
  (void)in_sizes; (void)n_in; (void)out_size; (void)ws_size;
  const float* x  = (const float*)d_in[0];
  const float* Wk = (const float*)d_in[1];
  const float* Wq = (const float*)d_in[2];
  const float* Wv = (const float*)d_in[3];
  const float* Wo = (const float*)d_in[4];
  const float* bo = (const float*)d_in[5];
  float* out = (float*)d_out;

  char* ws = (char*)d_ws;
  u16* xb   = (u16*)(ws);                       // 16MB (x cast, later attn-out)
  u16* kqv  = (u16*)(ws + ((size_t)16 << 20));  // 48MB [8192 x 3072] K|Q|V
  u16* wqkv = (u16*)(ws + ((size_t)64 << 20));  // 6MB  [3072 x 1024]
  u16* wob  = (u16*)(ws + ((size_t)70 << 20));  // 2MB -> 72MB total

  cast_all_kernel<<<dim3(12288), 256, 0, stream>>>(x, Wk, Wq, Wv, Wo, xb, wqkv, wob);

  // fused K/Q/V projection: [8192,3072] = [8192,1024] x [3072,1024]^T
  gemm256_kernel<<<dim3(384), 512, 0, stream>>>(xb, wqkv, kqv, 8192, 3072, 1024);

  // attention (writes into xb)
  attn_kernel<<<dim3(1024), 256, 0, stream>>>(kqv, xb);

  // final projection + bias, f32 out
  gemm_bt_kernel<1><<<dim3(8, 64), 256, 0, stream>>>(xb, wob, out, bo, 8192, 1024, 1024);
}